// Round 15
// baseline (68.632 us; speedup 1.0000x reference)
//
#include <hip/hip_runtime.h>

#define Nn 768
#define Dd 128
#define LDP 136   // padded bf16 row stride (272 B)

typedef __attribute__((ext_vector_type(8))) short bf16x8;
typedef __attribute__((ext_vector_type(4))) float f32x4;
typedef __attribute__((ext_vector_type(4))) int   i32x4;

static __device__ __forceinline__ unsigned short f2bf(float f) {
  unsigned int u = __builtin_bit_cast(unsigned int, f);
  u += 0x7fffu + ((u >> 16) & 1u);   // RNE
  return (unsigned short)(u >> 16);
}
static __device__ __forceinline__ float bf2f(unsigned short h) {
  unsigned int u = ((unsigned int)h) << 16;
  return __builtin_bit_cast(float, u);
}
// packed f32 pair -> [bf16(hi):bf16(lo)] in one VALU op (RNE)
static __device__ __forceinline__ unsigned int cvtpk(float lo, float hi) {
  unsigned int r;
  asm("v_cvt_pk_bf16_f32 %0, %1, %2" : "=v"(r) : "v"(lo), "v"(hi));
  return r;
}

// left[i][e] = sum_d x[i][d] * W_in[e][d] + b_in[e], stored bf16
__global__ __launch_bounds__(128)
void k_left(const float* __restrict__ x, const float* __restrict__ Win,
            const float* __restrict__ bin, unsigned short* __restrict__ left) {
  __shared__ float sx[Dd];
  const int i = blockIdx.x;
  const int e = threadIdx.x;
  sx[e] = x[i * Dd + e];
  __syncthreads();
  const float4* wrow = (const float4*)(Win + e * Dd);
  float a0 = 0.f, a1 = 0.f, a2 = 0.f, a3 = 0.f;
#pragma unroll
  for (int d4 = 0; d4 < Dd / 4; d4 += 4) {
    float4 w0 = wrow[d4+0], w1 = wrow[d4+1], w2 = wrow[d4+2], w3 = wrow[d4+3];
    a0 += sx[4*d4+ 0]*w0.x + sx[4*d4+ 1]*w0.y + sx[4*d4+ 2]*w0.z + sx[4*d4+ 3]*w0.w;
    a1 += sx[4*d4+ 4]*w1.x + sx[4*d4+ 5]*w1.y + sx[4*d4+ 6]*w1.z + sx[4*d4+ 7]*w1.w;
    a2 += sx[4*d4+ 8]*w2.x + sx[4*d4+ 9]*w2.y + sx[4*d4+10]*w2.z + sx[4*d4+11]*w2.w;
    a3 += sx[4*d4+12]*w3.x + sx[4*d4+13]*w3.y + sx[4*d4+14]*w3.z + sx[4*d4+15]*w3.w;
  }
  left[i * Dd + e] = f2bf(((a0 + a1) + (a2 + a3)) + bin[e]);
}

// out[i, j, e] = sum_d left[j][d] * (W_out[e][d]*left[i][d]) + b_out[e]
// Two i's per block (same jt): one barrier pair stages sB[2] (Wout loads
// reused across the pair); A-fragments preloaded once (shared by both i).
// Between i0-stores and i1-MFMA only ds_reads (lgkmcnt) -> no store drain.
__global__ __launch_bounds__(512, 4)
void k_outer(const unsigned short* __restrict__ left, const float* __restrict__ Wout,
             const float* __restrict__ bout, float* __restrict__ out) {
  __shared__ __attribute__((aligned(16))) unsigned short sB[2][128 * LDP];
  __shared__ float sLi[2][Dd];
  __shared__ float sBo[Dd];

  const int jt = blockIdx.x;   // 0..5
  const int ip = blockIdx.y;   // 0..383 -> i = ip*2, ip*2+1
  const int t  = threadIdx.x;  // 0..511

  if (t < 256) {
    const int h = t >> 7, e = t & 127;
    sLi[h][e] = bf2f(left[(ip * 2 + h) * Dd + e]);
    if (h == 0) sBo[e] = bout[e];
  }

  const int wid  = t >> 6;        // wave 0..7 -> j rows [wid*16, wid*16+16)
  const int lane = t & 63;
  const int l15  = lane & 15;
  const int kq   = (lane >> 4) * 8;

  // Preload the wave's 4 A-fragments (shared by both i's; left is L2-hot).
  const unsigned short* gA = left + (size_t)(jt * 128 + wid * 16 + l15) * Dd;
  bf16x8 A[4];
#pragma unroll
  for (int kb = 0; kb < 4; ++kb) A[kb] = *(const bf16x8*)(gA + kb * 32 + kq);

  __syncthreads();

  // Stage sB[0], sB[1]: thread covers col-chunk c8 x 4 rows (step 32),
  // Wout row loads hoisted and reused for both i's.
  {
    const int row = t >> 4;          // 0..31
    const int c8  = (t & 15) * 8;
    float l0[8], l1[8];
#pragma unroll
    for (int q = 0; q < 8; ++q) { l0[q] = sLi[0][c8 + q]; l1[q] = sLi[1][c8 + q]; }
#pragma unroll
    for (int it = 0; it < 4; ++it) {
      const int r = row + it * 32;   // 0..127
      const float4* wp = (const float4*)(Wout + r * Dd + c8);
      float4 w0 = wp[0], w1 = wp[1];
      i32x4 vb;
      vb[0] = (int)cvtpk(w0.x * l0[0], w0.y * l0[1]);
      vb[1] = (int)cvtpk(w0.z * l0[2], w0.w * l0[3]);
      vb[2] = (int)cvtpk(w1.x * l0[4], w1.y * l0[5]);
      vb[3] = (int)cvtpk(w1.z * l0[6], w1.w * l0[7]);
      *(i32x4*)(&sB[0][0] + r * LDP + c8) = vb;
      vb[0] = (int)cvtpk(w0.x * l1[0], w0.y * l1[1]);
      vb[1] = (int)cvtpk(w0.z * l1[2], w0.w * l1[3]);
      vb[2] = (int)cvtpk(w1.x * l1[4], w1.y * l1[5]);
      vb[3] = (int)cvtpk(w1.z * l1[6], w1.w * l1[7]);
      *(i32x4*)(&sB[1][0] + r * LDP + c8) = vb;
    }
  }
  __syncthreads();

  float bias[8];
#pragma unroll
  for (int n = 0; n < 8; ++n) bias[n] = sBo[n * 16 + l15];

#pragma unroll
  for (int h = 0; h < 2; ++h) {
    const int i = ip * 2 + h;

    f32x4 acc[8] = {};   // [e-chunk]
#pragma unroll
    for (int n = 0; n < 8; ++n) {
      const unsigned short* sBrow = &sB[h][0] + (n * 16 + l15) * LDP + kq;
#pragma unroll
      for (int kb = 0; kb < 4; ++kb) {
        bf16x8 b = *(const bf16x8*)(sBrow + kb * 32);
        acc[n] = __builtin_amdgcn_mfma_f32_16x16x32_bf16(A[kb], b, acc[n], 0, 0, 0);
      }
    }

    // Proven epilogue: row(j) = (lane>>4)*4 + r, col(e) = n*16 + l15.
#pragma unroll
    for (int r = 0; r < 4; ++r) {
      const int j = jt * 128 + wid * 16 + (lane >> 4) * 4 + r;
      float* orow = out + ((size_t)i * Nn + j) * Dd;
#pragma unroll
      for (int n = 0; n < 8; ++n) {
        orow[n * 16 + l15] = acc[n][r] + bias[n];
      }
    }
  }
}

extern "C" void kernel_launch(void* const* d_in, const int* in_sizes, int n_in,
                              void* d_out, int out_size, void* d_ws, size_t ws_size,
                              hipStream_t stream) {
  const float* x    = (const float*)d_in[0];
  const float* Win  = (const float*)d_in[1];
  const float* bin  = (const float*)d_in[2];
  const float* Wout = (const float*)d_in[3];
  const float* bout = (const float*)d_in[4];
  float* out = (float*)d_out;
  unsigned short* left = (unsigned short*)d_ws;  // 768*128 bf16 = 192 KiB

  k_left<<<Nn, Dd, 0, stream>>>(x, Win, bin, left);
  dim3 grid(Nn / 128, Nn / 2);
  k_outer<<<grid, 512, 0, stream>>>(left, Wout, bout, out);
}

// Round 17
// 62.284 us; speedup vs baseline: 1.1019x; 1.1019x over previous
//
#include <hip/hip_runtime.h>

#define Nn 768
#define Dd 128
#define LDP 136   // padded bf16 row stride in LDS (272 B)

typedef __attribute__((ext_vector_type(8))) short bf16x8;
typedef __attribute__((ext_vector_type(4))) float f32x4;
typedef __attribute__((ext_vector_type(4))) int   i32x4;

static __device__ __forceinline__ unsigned short f2bf(float f) {
  unsigned int u = __builtin_bit_cast(unsigned int, f);
  u += 0x7fffu + ((u >> 16) & 1u);   // RNE
  return (unsigned short)(u >> 16);
}
// packed f32 pair -> [bf16(hi):bf16(lo)] in one VALU op (RNE)
static __device__ __forceinline__ unsigned int cvtpk(float lo, float hi) {
  unsigned int r;
  asm("v_cvt_pk_bf16_f32 %0, %1, %2" : "=v"(r) : "v"(lo), "v"(hi));
  return r;
}
static __device__ __forceinline__ float bfhi(unsigned int u) {   // high bf16 -> f32
  return __builtin_bit_cast(float, u & 0xffff0000u);
}
static __device__ __forceinline__ float bflo(unsigned int u) {   // low bf16 -> f32
  return __builtin_bit_cast(float, u << 16);
}

// blocks 0..767: left[i][e] = x_i . Win[e] + bin[e]  (bf16 + f32 copies)
// blocks 768..775: convert Wout -> bf16 (row-major [128][128])
__global__ __launch_bounds__(128)
void k_left(const float* __restrict__ x, const float* __restrict__ Win,
            const float* __restrict__ bin, const float* __restrict__ Wout,
            unsigned short* __restrict__ left, float* __restrict__ left_f,
            unsigned short* __restrict__ wout_bf) {
  if (blockIdx.x >= Nn) {
    const int idx = (blockIdx.x - Nn) * 128 + threadIdx.x;   // 0..1023
    const float4* src = (const float4*)(Wout + idx * 16);
    float4 w0 = src[0], w1 = src[1], w2 = src[2], w3 = src[3];
    i32x4 o0, o1;
    o0[0] = (int)cvtpk(w0.x, w0.y); o0[1] = (int)cvtpk(w0.z, w0.w);
    o0[2] = (int)cvtpk(w1.x, w1.y); o0[3] = (int)cvtpk(w1.z, w1.w);
    o1[0] = (int)cvtpk(w2.x, w2.y); o1[1] = (int)cvtpk(w2.z, w2.w);
    o1[2] = (int)cvtpk(w3.x, w3.y); o1[3] = (int)cvtpk(w3.z, w3.w);
    *(i32x4*)(wout_bf + idx * 16)     = o0;
    *(i32x4*)(wout_bf + idx * 16 + 8) = o1;
    return;
  }
  __shared__ float sx[Dd];
  const int i = blockIdx.x;
  const int e = threadIdx.x;
  sx[e] = x[i * Dd + e];
  __syncthreads();
  const float4* wrow = (const float4*)(Win + e * Dd);
  float a0 = 0.f, a1 = 0.f, a2 = 0.f, a3 = 0.f;
#pragma unroll
  for (int d4 = 0; d4 < Dd / 4; d4 += 4) {
    float4 w0 = wrow[d4+0], w1 = wrow[d4+1], w2 = wrow[d4+2], w3 = wrow[d4+3];
    a0 += sx[4*d4+ 0]*w0.x + sx[4*d4+ 1]*w0.y + sx[4*d4+ 2]*w0.z + sx[4*d4+ 3]*w0.w;
    a1 += sx[4*d4+ 4]*w1.x + sx[4*d4+ 5]*w1.y + sx[4*d4+ 6]*w1.z + sx[4*d4+ 7]*w1.w;
    a2 += sx[4*d4+ 8]*w2.x + sx[4*d4+ 9]*w2.y + sx[4*d4+10]*w2.z + sx[4*d4+11]*w2.w;
    a3 += sx[4*d4+12]*w3.x + sx[4*d4+13]*w3.y + sx[4*d4+14]*w3.z + sx[4*d4+15]*w3.w;
  }
  const float v = ((a0 + a1) + (a2 + a3)) + bin[e];
  left_f[i * Dd + e] = v;
  left[i * Dd + e]   = f2bf(v);
}

// out[i, j, e] = sum_d (l_j[d]*l_i[d]) * Wout[e][d] + b_out[e]
// B operand = Wout (CONSTANT): LDS stage is a pure 32 KB copy, ONE barrier.
// A' = bf16(l_j .* l_i) computed per-thread in registers. FIX vs R16:
// lif now covers ALL k (lif[kb][m] = l_i[kb*32 + kq + m]).
__global__ __launch_bounds__(256, 4)
void k_outer(const unsigned short* __restrict__ left,
             const float* __restrict__ left_f,
             const unsigned short* __restrict__ wout_bf,
             const float* __restrict__ bout, float* __restrict__ out) {
  __shared__ __attribute__((aligned(16))) unsigned short sB[128 * LDP]; // Wout bf16

  const int jt = blockIdx.x;   // 0..5
  const int i  = blockIdx.y;   // 0..767
  const int t  = threadIdx.x;  // 0..255

  // ---- stage Wout tile: pure copy, 8 x (dwordx4 load + ds_write_b128)
#pragma unroll
  for (int it = 0; it < 8; ++it) {
    const int idx16 = t + it * 256;          // 16B-chunk index, 0..2047
    const int r  = idx16 >> 4;               // 0..127
    const int c8 = (idx16 & 15) * 8;
    *(i32x4*)(sB + r * LDP + c8) = *(const i32x4*)(wout_bf + r * Dd + c8);
  }

  const int wid  = t >> 6;        // wave 0..3 -> j rows [wid*32, wid*32+32)
  const int lane = t & 63;
  const int l15  = lane & 15;
  const int kq   = (lane >> 4) * 8;

  float bias[8];
#pragma unroll
  for (int n = 0; n < 8; ++n) bias[n] = bout[n * 16 + l15];

  // l_i values this lane needs: lif[kb][m] = l_i[kb*32 + kq + m], m=0..7
  float lif[4][8];
#pragma unroll
  for (int kb = 0; kb < 4; ++kb) {
    const float4* lp = (const float4*)(left_f + i * Dd + kb * 32 + kq);
    float4 f0 = lp[0], f1 = lp[1];
    lif[kb][0]=f0.x; lif[kb][1]=f0.y; lif[kb][2]=f0.z; lif[kb][3]=f0.w;
    lif[kb][4]=f1.x; lif[kb][5]=f1.y; lif[kb][6]=f1.z; lif[kb][7]=f1.w;
  }

  // A'[jb][kb] = bf16(l_j .* l_i) fragments (j = jt*128 + wid*32 + jb*16 + l15)
  bf16x8 Ap[2][4];
#pragma unroll
  for (int jb = 0; jb < 2; ++jb) {
    const unsigned short* gL = left + (size_t)(jt * 128 + wid * 32 + jb * 16 + l15) * Dd + kq;
#pragma unroll
    for (int kb = 0; kb < 4; ++kb) {
      i32x4 a = *(const i32x4*)(gL + kb * 32);
      i32x4 vb;
#pragma unroll
      for (int w = 0; w < 4; ++w) {
        const unsigned int u = (unsigned int)a[w];
        vb[w] = (int)cvtpk(bflo(u) * lif[kb][2*w], bfhi(u) * lif[kb][2*w+1]);
      }
      Ap[jb][kb] = __builtin_bit_cast(bf16x8, vb);
    }
  }

  __syncthreads();   // sB copy complete; lif dead from here on

  f32x4 acc[2][8] = {};   // [j-frag][e-chunk]
#pragma unroll
  for (int n = 0; n < 8; ++n) {
    const unsigned short* sBrow = sB + (n * 16 + l15) * LDP + kq;
#pragma unroll
    for (int kb = 0; kb < 4; ++kb) {
      bf16x8 b = *(const bf16x8*)(sBrow + kb * 32);
      acc[0][n] = __builtin_amdgcn_mfma_f32_16x16x32_bf16(Ap[0][kb], b, acc[0][n], 0, 0, 0);
      acc[1][n] = __builtin_amdgcn_mfma_f32_16x16x32_bf16(Ap[1][kb], b, acc[1][n], 0, 0, 0);
    }
  }

  // R9-proven epilogue: row(j) = (lane>>4)*4 + r, col(e) = n*16 + l15.
#pragma unroll
  for (int jb = 0; jb < 2; ++jb) {
#pragma unroll
    for (int r = 0; r < 4; ++r) {
      const int j = jt * 128 + wid * 32 + jb * 16 + (lane >> 4) * 4 + r;
      float* orow = out + ((size_t)i * Nn + j) * Dd;
#pragma unroll
      for (int n = 0; n < 8; ++n) {
        orow[n * 16 + l15] = acc[jb][n][r] + bias[n];
      }
    }
  }
}

extern "C" void kernel_launch(void* const* d_in, const int* in_sizes, int n_in,
                              void* d_out, int out_size, void* d_ws, size_t ws_size,
                              hipStream_t stream) {
  const float* x    = (const float*)d_in[0];
  const float* Win  = (const float*)d_in[1];
  const float* bin  = (const float*)d_in[2];
  const float* Wout = (const float*)d_in[3];
  const float* bout = (const float*)d_in[4];
  float* out = (float*)d_out;

  unsigned short* left    = (unsigned short*)d_ws;                  // 192 KiB
  float*          left_f  = (float*)((char*)d_ws + 256 * 1024);     // 384 KiB
  unsigned short* wout_bf = (unsigned short*)((char*)d_ws + 768 * 1024); // 32 KiB

  k_left<<<Nn + 8, Dd, 0, stream>>>(x, Win, bin, Wout, left, left_f, wout_bf);
  dim3 grid(Nn / 128, Nn);
  k_outer<<<grid, 256, 0, stream>>>(left, left_f, wout_bf, bout, out);
}